// Round 10
// baseline (186.520 us; speedup 1.0000x reference)
//
#include <hip/hip_runtime.h>

#define DIM   128
#define HALF  64          // columns per slice (2 slices, XCD-parity L2 residency)
#define CPT   256         // chars per wave-chunk
#define TAIL  64          // lookahead window for cross-chunk tails
#define WPB   4           // waves per block
#define NSEG  22          // deferred-ring capacity (flush ordinals < NSEG)
#define NHID  (CPT + 1)

// out = N - <H,T>_F / (||H||_F ||T||_F).  T never materialized globally.
// Lane = column of a 64-col slice; control is wave-uniform (SGPR ballot masks
// -> scalar bit test). Flushes DEFER the dot: acc -> wave-private LDS ring
// (ds_write only, no dependent loads in the hot loop); a post-loop epilogue
// gathers head rows for all ring entries with 8 independent loads in flight.
// Char 0 of each chunk is always a boundary; ordinal 0 is always dropped
// (it is either empty or the previous chunk's continuation).
__global__ __launch_bounds__(256) void fused_kernel(
    const float* __restrict__ char_emb,
    const float* __restrict__ ent,
    const int* __restrict__ head_ids,
    const int* __restrict__ char_ids,
    const int* __restrict__ seg_ids,
    float* __restrict__ pb,        // [gridDim.x*3] block partials: ht,tt,hh
    int total_chars, int n_triples, int hh_per_block)
{
    __shared__ __align__(16) int s_off[WPB][CPT];        // (cid<<9)+sco
    __shared__ int s_hid[WPB][NHID];   // head ids in flush-ordinal order
    __shared__ float s_ring[WPB][NSEG * 64];             // deferred acc rows
    __shared__ float r_scr[3][WPB];

    const int tid  = threadIdx.x;
    const int lane = tid & 63;
    const int wid  = tid >> 6;
    const int colb = lane << 2;               // byte offset of lane's column

    float ht = 0.f, tt = 0.f, hh = 0.f;

    const int slice = blockIdx.x & 1;         // XCD-parity slice mapping
    const int sco   = slice << 8;             // slice*64 cols*4B
    const int chunk = (blockIdx.x >> 1) * WPB + wid;
    const int start = chunk * CPT;
    const int len   = min(CPT, total_chars - start);
    const int sl    = min(CPT + TAIL, total_chars - start);
    const char* cb  = (const char*)char_emb;
    const float* ee = ent + slice * HALF + lane;

    // ---- staging: gather offsets, boundary masks (SGPR), head ids (LDS) ----
    unsigned long long mk[4] = {0ull, 0ull, 0ull, 0ull};
    int nb = 0;                               // boundary count (>=1)
    if (len == CPT) {
        for (int c = lane; c < CPT; c += 64)
            s_off[wid][c] = (char_ids[start + c] << 9) + sco;
#pragma unroll
        for (int grp = 0; grp < 4; ++grp) {
            const int c = start + grp * 64 + lane;
            const int s1 = seg_ids[c];
            int sp = __shfl_up(s1, 1);
            if (lane == 0) sp = (c > 0) ? seg_ids[c - 1] : s1;
            const bool bnd = ((grp == 0) && (lane == 0)) || (s1 != sp);
            const unsigned long long m = __ballot(bnd);
            if (bnd) {
                const int ord = nb + __builtin_amdgcn_mbcnt_hi(
                    (unsigned)(m >> 32),
                    __builtin_amdgcn_mbcnt_lo((unsigned)m, 0));
                s_hid[wid][ord] = (c > 0) ? head_ids[sp] : 0; // finishing seg's head
            }
            mk[grp] = m;
            nb += __popcll(m);
        }
        if (lane == 0)                                   // final segment's head
            s_hid[wid][nb] = head_ids[seg_ids[start + CPT - 1]];
    }
    __syncthreads();

    if (len == CPT) {
        // -------- fast path --------
        const int fin = seg_ids[start + CPT - 1];        // uniform
        float* ring = &s_ring[wid][0];
        float acc = 0.f;
        int f = 0;
        float vA[16], vB[16];

#define PF(BUF, B) { \
    _Pragma("unroll") \
    for (int q = 0; q < 4; ++q) { \
        const int4 o4 = *(const int4*)&s_off[wid][(B) * 16 + q * 4]; \
        BUF[q * 4 + 0] = *(const float*)(cb + (size_t)(unsigned)(o4.x + colb)); \
        BUF[q * 4 + 1] = *(const float*)(cb + (size_t)(unsigned)(o4.y + colb)); \
        BUF[q * 4 + 2] = *(const float*)(cb + (size_t)(unsigned)(o4.z + colb)); \
        BUF[q * 4 + 3] = *(const float*)(cb + (size_t)(unsigned)(o4.w + colb)); \
    } }

#define CS(BUF, B) { \
    _Pragma("unroll") \
    for (int j = 0; j < 16; ++j) { \
        if (mk[(B) >> 2] & (1ull << (((B) & 3) * 16 + j))) {  /* scalar test */ \
            if (f < NSEG) { \
                ring[f * 64 + lane] = acc;          /* ds_write only */ \
            } else {                                 /* rare overflow */ \
                const int hid = s_hid[wid][f]; \
                const float hv = ee[(size_t)(unsigned)hid * DIM]; \
                ht = fmaf(hv, acc, ht); tt = fmaf(acc, acc, tt); \
            } \
            ++f; acc = 0.f; \
        } \
        acc += BUF[j]; \
    } }

        PF(vA, 0)
#pragma unroll
        for (int B = 0; B < 16; ++B) {
            if (B + 1 < 16) { if (B & 1) { PF(vA, B + 1) } else { PF(vB, B + 1) } }
            if (B & 1) { CS(vB, B) } else { CS(vA, B) }
        }
#undef PF
#undef CS

        // ---- tail: final segment may continue past chunk end ----
        {
            int e = CPT;
            bool ended = false;
            while (e < sl) {
                const int idx = e + lane;
                const bool differ = (idx < sl) && (seg_ids[start + idx] != fin);
                const unsigned long long bm = __ballot(differ);
                const int run = bm ? (__ffsll((long long)bm) - 1)
                                   : min(64, sl - e);
                for (int j = 0; j < run; j += 4) {
                    const int mm2 = min(4, run - j);
                    float vv[4];
#pragma unroll
                    for (int k = 0; k < 4; ++k) {
                        if (k < mm2)
                            vv[k] = *(const float*)(cb + (size_t)(unsigned)(
                                (char_ids[start + e + j + k] << 9) + sco + colb));
                    }
                    for (int k = 0; k < mm2; ++k) acc += vv[k];
                }
                e += run;
                if (bm) { ended = true; break; }
            }
            if (!ended && start + sl < total_chars) {
                int gg = start + sl;                 // very rare long run
                while (gg < total_chars && seg_ids[gg] == fin) {
                    acc += *(const float*)(cb + (size_t)(unsigned)(
                        (char_ids[gg] << 9) + sco + colb));
                    ++gg;
                }
            }
        }
        // final flush (ordinal nb)
        if (nb < NSEG) {
            ring[nb * 64 + lane] = acc;
        } else {
            const int hid = s_hid[wid][nb];
            const float hv = ee[(size_t)(unsigned)hid * DIM];
            ht = fmaf(hv, acc, ht); tt = fmaf(acc, acc, tt);
        }

        // ---- epilogue: ring ordinals 1..min(nb,NSEG-1), 8 loads in flight ----
        const int fe = min(nb, NSEG - 1);
        for (int b0 = 1; b0 <= fe; b0 += 8) {
            const int mc = min(8, fe - b0 + 1);
            float trb[8], hvb[8];
#pragma unroll
            for (int q = 0; q < 8; ++q) {
                if (q < mc) {
                    trb[q] = ring[(b0 + q) * 64 + lane];
                    const int hid = s_hid[wid][b0 + q];
                    hvb[q] = ee[(size_t)(unsigned)hid * DIM];
                }
            }
            for (int q = 0; q < mc; ++q) {
                ht = fmaf(hvb[q], trb[q], ht);
                tt = fmaf(trb[q], trb[q], tt);
            }
        }
    } else if (len > 0) {
        // -------- rare fallback (partial last chunk): scalar per char --------
        const float* cembF = char_emb + slice * HALF + lane;
        int p = 0;
        if (start > 0) {
            const int prev = seg_ids[start - 1];
            while (p < len && seg_ids[start + p] == prev) ++p;
        }
        if (p < len) {
            int cur = seg_ids[start + p];
            float acc = 0.f;
            float hv = ee[(size_t)(unsigned)head_ids[cur] * DIM];
            for (int c = p; c < len; ++c) {
                const int sid = seg_ids[start + c];
                if (sid != cur) {
                    ht += hv * acc; tt += acc * acc;
                    acc = 0.f; cur = sid;
                    hv = ee[(size_t)(unsigned)head_ids[cur] * DIM];
                }
                acc += cembF[(size_t)(unsigned)char_ids[start + c] * DIM];
            }
            int gg = start + len;
            while (gg < total_chars && seg_ids[gg] == cur) {
                acc += cembF[(size_t)(unsigned)char_ids[gg] * DIM];
                ++gg;
            }
            ht += hv * acc; tt += acc * acc;
        }
    }

    // -------- hh strip for this block (covers empty segments exactly) --------
    {
        const float4* e4 = (const float4*)ent;
        const long base = (long)blockIdx.x * hh_per_block * 32;
        const long lim  = (long)n_triples * 32;
        for (int s = tid; s < hh_per_block * 32; s += 256) {
            const long f2 = base + s;
            if (f2 < lim) {
                const int row = (int)(f2 >> 5);
                const int hid = head_ids[row];
                const float4 v = e4[(size_t)hid * 32 + (int)(f2 & 31)];
                hh += v.x * v.x + v.y * v.y + v.z * v.z + v.w * v.w;
            }
        }
    }

    // -------- block reduce -> per-block partials (no atomics, no memset) ----
#pragma unroll
    for (int off = 32; off > 0; off >>= 1) {
        ht += __shfl_down(ht, off);
        tt += __shfl_down(tt, off);
        hh += __shfl_down(hh, off);
    }
    if (lane == 0) { r_scr[0][wid] = ht; r_scr[1][wid] = tt; r_scr[2][wid] = hh; }
    __syncthreads();
    if (tid == 0) {
        float a = 0.f, b = 0.f, c = 0.f;
#pragma unroll
        for (int w = 0; w < WPB; ++w) {
            a += r_scr[0][w]; b += r_scr[1][w]; c += r_scr[2][w];
        }
        pb[blockIdx.x * 3 + 0] = a;
        pb[blockIdx.x * 3 + 1] = b;
        pb[blockIdx.x * 3 + 2] = c;
    }
}

// final reduce: sums partials in double, writes N - ht/sqrt(hh*tt)
__global__ __launch_bounds__(256) void reduce_kernel(
    const float* __restrict__ pb, int nb, float* __restrict__ out,
    int n_triples)
{
    double ht = 0.0, tt = 0.0, hh = 0.0;
    for (int i = threadIdx.x; i < nb; i += 256) {
        ht += (double)pb[i * 3 + 0];
        tt += (double)pb[i * 3 + 1];
        hh += (double)pb[i * 3 + 2];
    }
#pragma unroll
    for (int off = 32; off > 0; off >>= 1) {
        ht += __shfl_down(ht, off);
        tt += __shfl_down(tt, off);
        hh += __shfl_down(hh, off);
    }
    __shared__ double sd[3][4];
    const int wid = threadIdx.x >> 6;
    if ((threadIdx.x & 63) == 0) { sd[0][wid] = ht; sd[1][wid] = tt; sd[2][wid] = hh; }
    __syncthreads();
    if (threadIdx.x == 0) {
        double a = 0.0, b = 0.0, c = 0.0;
        for (int w = 0; w < 4; ++w) { a += sd[0][w]; b += sd[1][w]; c += sd[2][w]; }
        out[0] = (float)((double)n_triples - a / sqrt(c * b));
    }
}

extern "C" void kernel_launch(void* const* d_in, const int* in_sizes, int n_in,
                              void* d_out, int out_size, void* d_ws, size_t ws_size,
                              hipStream_t stream)
{
    const float* char_emb = (const float*)d_in[0];
    const float* ent_emb  = (const float*)d_in[1];
    const int* head_ids   = (const int*)d_in[2];
    const int* char_ids   = (const int*)d_in[3];
    const int* seg_ids    = (const int*)d_in[4];
    const int n_triples   = in_sizes[2];
    const int total_chars = in_sizes[3];

    const int n_chunks = (total_chars + CPT - 1) / CPT;
    const int bps = (n_chunks + WPB - 1) / WPB;
    const int nsb = 2 * bps;                       // x2 slices
    const int hhpb = (n_triples + nsb - 1) / nsb;

    float* pb = (float*)d_ws;                      // nsb*3 floats

    fused_kernel<<<nsb, 256, 0, stream>>>(char_emb, ent_emb, head_ids,
                                          char_ids, seg_ids, pb,
                                          total_chars, n_triples, hhpb);
    reduce_kernel<<<1, 256, 0, stream>>>(pb, nsb, (float*)d_out, n_triples);
}